// Round 1
// baseline (393.857 us; speedup 1.0000x reference)
//
#include <hip/hip_runtime.h>

// Problem dims (fixed by the reference)
#define N_DIM 32
#define C_DIM 64
#define T_DIM 512
#define V_DIM 25
#define H_DIM 3
#define TL 4            // t-values per block in pass 1
#define VPAD 28         // pad 25 -> 28 floats (16B-aligned rows)
#define NTV (N_DIM * T_DIM * V_DIM)   // 409600 elements per channel
#define NBLK1 (N_DIM * (T_DIM / TL))  // 4096 blocks in pass 1
#define BN_EPS 1e-5f

// ---------------------------------------------------------------------------
// Pass 1: out_pre[n,o,t,v] = sum_{h,c,u} W[h,o,c] * A[h,v,u] * x[n,c,t,u]
// (bias omitted: a per-channel constant cancels exactly through BatchNorm)
// Also emits per-block, per-channel partial {sum, sumsq} for BN stats
// (deterministic: no float atomics).
// ---------------------------------------------------------------------------
__global__ __launch_bounds__(256) void gcn_pass1(
    const float* __restrict__ x, const float* __restrict__ A,
    const float* __restrict__ W, float* __restrict__ out_pre,
    float* __restrict__ partial)
{
    __shared__ float x_s[TL * C_DIM * VPAD];       // [tl][c][u]   28,672 B
    __shared__ float wt_s[C_DIM * 65];             // [c][o] (one h) 16,640 B
    __shared__ float a_s[H_DIM * V_DIM * VPAD];    // [h][v][u]     8,400 B
    __shared__ float red_s[256];                   //               1,024 B

    const int blk = blockIdx.x;
    const int n   = blk >> 7;            // 128 t-groups per n
    const int t0  = (blk & 127) * TL;
    const int tid = threadIdx.x;
    const int o   = tid & 63;            // lanes 0..63 of a wave = all o
    const int tl  = tid >> 6;

    // ---- stage x tile: x[n, 0:64, t0:t0+TL, 0:25] (contiguous 100-float runs)
    const float* xn = x + (size_t)n * (C_DIM * T_DIM * V_DIM);
    for (int e = tid; e < TL * C_DIM * V_DIM; e += 256) {
        int c = e / (TL * V_DIM);
        int r = e % (TL * V_DIM);
        int tll = r / V_DIM, u = r % V_DIM;
        x_s[(tll * C_DIM + c) * VPAD + u] = xn[c * (T_DIM * V_DIM) + t0 * V_DIM + r];
    }
    // ---- stage A: [h][v][u]
    for (int e = tid; e < H_DIM * V_DIM * V_DIM; e += 256) {
        int h = e / (V_DIM * V_DIM);
        int r = e % (V_DIM * V_DIM);
        int v = r / V_DIM, u = r % V_DIM;
        a_s[(h * V_DIM + v) * VPAD + u] = A[e];
    }

    float acc[V_DIM];
    #pragma unroll
    for (int v = 0; v < V_DIM; ++v) acc[v] = 0.f;

    const float* xrowbase = &x_s[tl * C_DIM * VPAD];

    for (int h = 0; h < H_DIM; ++h) {
        __syncthreads();
        // stage W_h transposed: wt_s[c][o] <- W[h][o][c] (coalesced read,
        // stride-65 LDS write => conflict-free)
        for (int e = tid; e < C_DIM * C_DIM; e += 256) {
            int oo = e >> 6, c = e & 63;
            wt_s[c * 65 + oo] = W[h * C_DIM * C_DIM + e];
        }
        __syncthreads();

        // s[u] = sum_c W[h,o,c] * x[n,c,t,u]  (x reads are wave-uniform)
        float s[V_DIM];
        #pragma unroll
        for (int u = 0; u < V_DIM; ++u) s[u] = 0.f;
        for (int c = 0; c < C_DIM; ++c) {
            float w = wt_s[c * 65 + o];
            const float* xr = xrowbase + c * VPAD;
            #pragma unroll
            for (int u = 0; u < V_DIM; ++u) s[u] = fmaf(w, xr[u], s[u]);
        }
        // acc[v] += sum_u A[h,v,u] * s[u]   (A reads wave-uniform)
        const float* ah = &a_s[h * V_DIM * VPAD];
        #pragma unroll
        for (int v = 0; v < V_DIM; ++v) {
            float av = 0.f;
            #pragma unroll
            for (int u = 0; u < V_DIM; ++u) av = fmaf(ah[v * VPAD + u], s[u], av);
            acc[v] += av;
        }
    }

    // ---- store pre-BN output (25 contiguous floats per thread)
    float* op = out_pre + (size_t)((n * C_DIM + o) * T_DIM + (t0 + tl)) * V_DIM;
    #pragma unroll
    for (int v = 0; v < V_DIM; ++v) op[v] = acc[v];

    // ---- per-channel partial stats (sum over this thread's 25 v's,
    //      then over the TL=4 threads sharing each o)
    float lsum = 0.f, lsq = 0.f;
    #pragma unroll
    for (int v = 0; v < V_DIM; ++v) { lsum += acc[v]; lsq = fmaf(acc[v], acc[v], lsq); }

    red_s[tid] = lsum;
    __syncthreads();
    if (tid < 64)
        partial[blk * 128 + tid] =
            red_s[tid] + red_s[tid + 64] + red_s[tid + 128] + red_s[tid + 192];
    __syncthreads();
    red_s[tid] = lsq;
    __syncthreads();
    if (tid < 64)
        partial[blk * 128 + 64 + tid] =
            red_s[tid] + red_s[tid + 64] + red_s[tid + 128] + red_s[tid + 192];
}

// ---------------------------------------------------------------------------
// Pass 2: reduce partials -> per-channel mean and rsqrt(var+eps)
// ---------------------------------------------------------------------------
__global__ __launch_bounds__(256) void gcn_stats(
    const float* __restrict__ partial, float* __restrict__ stats)
{
    const int o = blockIdx.x;      // 64 blocks, one per channel
    const int tid = threadIdx.x;
    float s = 0.f, q = 0.f;
    for (int blk = tid; blk < NBLK1; blk += 256) {
        s += partial[blk * 128 + o];
        q += partial[blk * 128 + 64 + o];
    }
    __shared__ float rs[256], rq[256];
    rs[tid] = s; rq[tid] = q;
    __syncthreads();
    for (int off = 128; off > 0; off >>= 1) {
        if (tid < off) { rs[tid] += rs[tid + off]; rq[tid] += rq[tid + off]; }
        __syncthreads();
    }
    if (tid == 0) {
        float mean = rs[0] / (float)NTV;
        float var  = rq[0] / (float)NTV - mean * mean;   // biased, like jnp.var
        stats[o]      = mean;
        stats[64 + o] = rsqrtf(var + BN_EPS);
    }
}

// ---------------------------------------------------------------------------
// Pass 3: out = relu(gamma*(pre-mean)*rsig + beta + x), in place, float4
// ---------------------------------------------------------------------------
__global__ __launch_bounds__(256) void gcn_finalize(
    const float* __restrict__ x, const float* __restrict__ gamma,
    const float* __restrict__ beta, const float* __restrict__ stats,
    float* __restrict__ out)
{
    const int total4 = (N_DIM * C_DIM * T_DIM * V_DIM) / 4;
    for (int i = blockIdx.x * blockDim.x + threadIdx.x; i < total4;
         i += gridDim.x * blockDim.x) {
        int chan = ((i * 4) / (T_DIM * V_DIM)) & 63;   // 12800 elems/channel, %4==0
        float4 p  = ((const float4*)out)[i];
        float4 xv = ((const float4*)x)[i];
        float m = stats[chan], r = stats[64 + chan];
        float g = gamma[chan] * r;
        float bc = beta[chan] - g * m;
        p.x = fmaxf(fmaf(g, p.x, bc) + xv.x, 0.f);
        p.y = fmaxf(fmaf(g, p.y, bc) + xv.y, 0.f);
        p.z = fmaxf(fmaf(g, p.z, bc) + xv.z, 0.f);
        p.w = fmaxf(fmaf(g, p.w, bc) + xv.w, 0.f);
        ((float4*)out)[i] = p;
    }
}

extern "C" void kernel_launch(void* const* d_in, const int* in_sizes, int n_in,
                              void* d_out, int out_size, void* d_ws, size_t ws_size,
                              hipStream_t stream) {
    const float* x     = (const float*)d_in[0];
    const float* A     = (const float*)d_in[1];
    const float* W     = (const float*)d_in[2];
    // d_in[3] = b : unused — per-channel bias cancels exactly through BatchNorm
    const float* gamma = (const float*)d_in[4];
    const float* beta  = (const float*)d_in[5];
    float* out = (float*)d_out;

    float* partial = (float*)d_ws;               // NBLK1 * 128 floats = 2 MB
    float* stats   = partial + NBLK1 * 128;      // 128 floats

    gcn_pass1<<<NBLK1, 256, 0, stream>>>(x, A, W, out, partial);
    gcn_stats<<<64, 256, 0, stream>>>(partial, stats);
    gcn_finalize<<<2048, 256, 0, stream>>>(x, gamma, beta, stats, out);
}

// Round 2
// 175.028 us; speedup vs baseline: 2.2503x; 2.2503x over previous
//
#include <hip/hip_runtime.h>

// Problem dims (fixed by the reference)
#define N_DIM 32
#define C_DIM 64
#define T_DIM 512
#define V_DIM 25
#define H_DIM 3
#define TT 4                              // t-values per block in pass 1
#define NBLK (N_DIM * (T_DIM / TT))       // 4096 blocks in pass 1
#define NTV (N_DIM * T_DIM * V_DIM)       // 409600 elements per channel
#define BN_EPS 1e-5f

typedef float f32x4 __attribute__((ext_vector_type(4)));
typedef short bf16x8 __attribute__((ext_vector_type(8)));

__device__ __forceinline__ short f2bf(float f) {
    unsigned u = __float_as_uint(f);
    u = (u + 0x7FFFu + ((u >> 16) & 1u)) >> 16;   // round-to-nearest-even
    return (short)u;
}

// ---------------------------------------------------------------------------
// Pass 1 (MFMA): out_pre[n,o,t,v] = sum_{h,c,u} W[h,o,c] A[h,v,u] x[n,c,t,u]
//   GEMM1 per head:  y[o][(t,u)]  = W_h[o][c] * x[c][(t,u)]     (K=64)
//   GEMM2 per head:  outT[v][(o,t)] += A_h[v][u] * yT[u][(o,t)] (K=25 pad 32)
// bias dropped: a per-channel constant cancels exactly through BatchNorm.
// Each wave owns o in [16w,16w+16) for BOTH gemms -> no syncs in head loop.
// Also emits deterministic per-block per-channel {sum,sumsq} partials.
// ---------------------------------------------------------------------------
__global__ __launch_bounds__(256) void gcn_pass1(
    const float* __restrict__ x, const float* __restrict__ A,
    const float* __restrict__ W, float* __restrict__ out_pre,
    float* __restrict__ partial)
{
    // x transposed tile: [tu=100 (pad 112)][c=64 (pad 72)]  -> 16,128 B
    __shared__ __align__(16) short x_sT[112 * 72];
    // y tile: [o=64][t=4][u pad 40]                          -> 20,480 B
    __shared__ __align__(16) short y_s[64 * 4 * 40];

    const int blk  = blockIdx.x;
    const int n    = blk >> 7;             // 128 t-groups per n
    const int t0   = (blk & 127) * TT;
    const int tid  = threadIdx.x;
    const int lane = tid & 63;
    const int w    = tid >> 6;             // wave 0..3
    const int l15  = lane & 15;
    const int hi   = lane >> 4;

    // ---- zero this wave's y_s region (o in [16w,16w+16)) : 1280 ints
    {
        int* yz = (int*)(y_s + w * (16 * 4 * 40));
        #pragma unroll
        for (int e = 0; e < 20; ++e) yz[lane + e * 64] = 0;
    }

    // ---- preload W fragments (A-operand of GEMM1): this wave's o-range
    // lane l: o = 16w + l15, k(c) = s*32 + hi*8 + i
    bf16x8 wf[H_DIM][2];
    #pragma unroll
    for (int h = 0; h < H_DIM; ++h)
        #pragma unroll
        for (int s = 0; s < 2; ++s) {
            const f32x4* wp = (const f32x4*)(W + h * 4096 + (16 * w + l15) * 64
                                             + s * 32 + hi * 8);
            f32x4 lo = wp[0], hiv = wp[1];
            bf16x8 f;
            #pragma unroll
            for (int i = 0; i < 4; ++i) { f[i] = f2bf(lo[i]); f[4 + i] = f2bf(hiv[i]); }
            wf[h][s] = f;
        }

    // ---- preload A fragments (A-operand of GEMM2)
    // lane l: v = vt*16 + l15, k(u) = hi*8 + i ; zero-pad v>=25 or u>=25
    bf16x8 af[H_DIM][2];
    #pragma unroll
    for (int h = 0; h < H_DIM; ++h)
        #pragma unroll
        for (int vt = 0; vt < 2; ++vt) {
            int v = vt * 16 + l15;
            bf16x8 f;
            #pragma unroll
            for (int i = 0; i < 8; ++i) {
                int u = hi * 8 + i;
                float val = (v < 25 && u < 25) ? A[h * 625 + v * 25 + u] : 0.f;
                f[i] = f2bf(val);
            }
            af[h][vt] = f;
        }

    // ---- stage x transposed: x_sT[tu][c] = bf16(x[n][c][t0 + tu/25][tu%25])
    for (int e = tid; e < 1600; e += 256) {
        int c = e / 25;
        int q = e - c * 25;
        const f32x4 X = *(const f32x4*)(x + (((size_t)(n * 64 + c)) * 512 + t0) * 25
                                        + 4 * q);
        #pragma unroll
        for (int i = 0; i < 4; ++i)
            x_sT[(4 * q + i) * 72 + c] = f2bf(X[i]);
    }
    __syncthreads();

    f32x4 acc2[4][2];
    #pragma unroll
    for (int q = 0; q < 4; ++q)
        #pragma unroll
        for (int vt = 0; vt < 2; ++vt)
            acc2[q][vt] = f32x4{0.f, 0.f, 0.f, 0.f};

    for (int h = 0; h < H_DIM; ++h) {
        // ---- GEMM1: D[m=o_local][n=tu] ; write y_s (own o rows only)
        #pragma unroll
        for (int nt = 0; nt < 7; ++nt) {
            const bf16x8 xf0 = *(const bf16x8*)&x_sT[(nt * 16 + l15) * 72 + hi * 8];
            const bf16x8 xf1 = *(const bf16x8*)&x_sT[(nt * 16 + l15) * 72 + 32 + hi * 8];
            f32x4 acc = {0.f, 0.f, 0.f, 0.f};
            acc = __builtin_amdgcn_mfma_f32_16x16x32_bf16(wf[h][0], xf0, acc, 0, 0, 0);
            acc = __builtin_amdgcn_mfma_f32_16x16x32_bf16(wf[h][1], xf1, acc, 0, 0, 0);
            int col = nt * 16 + l15;
            if (col < 100) {
                int t = col / 25, u = col - t * 25;
                #pragma unroll
                for (int j = 0; j < 4; ++j) {
                    int o = 16 * w + hi * 4 + j;
                    y_s[(o * 4 + t) * 40 + u] = f2bf(acc[j]);
                }
            }
        }
        // ---- GEMM2: D[m=v][n=ot] ; reads only this wave's y_s rows
        #pragma unroll
        for (int q = 0; q < 4; ++q) {
            int ot = (4 * w + q) * 16 + l15;      // o = ot>>2 in [16w,16w+16)
            const bf16x8 yf = *(const bf16x8*)&y_s[(ot) * 40 + hi * 8];
            acc2[q][0] = __builtin_amdgcn_mfma_f32_16x16x32_bf16(af[h][0], yf,
                                                                 acc2[q][0], 0, 0, 0);
            acc2[q][1] = __builtin_amdgcn_mfma_f32_16x16x32_bf16(af[h][1], yf,
                                                                 acc2[q][1], 0, 0, 0);
        }
    }

    // ---- store pre-BN output: lane holds outT[v=vt*16+hi*4+j][ot]
    #pragma unroll
    for (int q = 0; q < 4; ++q) {
        int ot = (4 * w + q) * 16 + l15;
        int o  = ot >> 2;
        int t  = t0 + (ot & 3);
        float* op = out_pre + ((size_t)(n * 64 + o) * 512 + t) * 25;
        #pragma unroll
        for (int vt = 0; vt < 2; ++vt)
            #pragma unroll
            for (int j = 0; j < 4; ++j) {
                int v = vt * 16 + hi * 4 + j;
                if (v < 25) op[v] = acc2[q][vt][j];
            }
    }

    // ---- per-channel partial stats: reduce lanes sharing o (bits 0,1,4,5)
    #pragma unroll
    for (int q = 0; q < 4; ++q) {
        float s = 0.f, sq = 0.f;
        #pragma unroll
        for (int j = 0; j < 4; ++j) {
            float v0 = acc2[q][0][j];
            s += v0; sq = fmaf(v0, v0, sq);
        }
        #pragma unroll
        for (int j = 0; j < 4; ++j) {
            int v = 16 + hi * 4 + j;
            float v1 = acc2[q][1][j];
            if (v < 25) { s += v1; sq = fmaf(v1, v1, sq); }
        }
        s  += __shfl_xor(s, 1);  sq += __shfl_xor(sq, 1);
        s  += __shfl_xor(s, 2);  sq += __shfl_xor(sq, 2);
        s  += __shfl_xor(s, 16); sq += __shfl_xor(sq, 16);
        s  += __shfl_xor(s, 32); sq += __shfl_xor(sq, 32);
        if ((l15 & 3) == 0 && hi == 0) {
            int o = 16 * w + 4 * q + (l15 >> 2);
            partial[blk * 128 + o]      = s;
            partial[blk * 128 + 64 + o] = sq;
        }
    }
}

// ---------------------------------------------------------------------------
// Pass 2: reduce partials -> per-channel mean and rsqrt(var+eps)
// ---------------------------------------------------------------------------
__global__ __launch_bounds__(256) void gcn_stats(
    const float* __restrict__ partial, float* __restrict__ stats)
{
    const int o = blockIdx.x;      // 64 blocks, one per channel
    const int tid = threadIdx.x;
    float s = 0.f, q = 0.f;
    for (int blk = tid; blk < NBLK; blk += 256) {
        s += partial[blk * 128 + o];
        q += partial[blk * 128 + 64 + o];
    }
    __shared__ float rs[256], rq[256];
    rs[tid] = s; rq[tid] = q;
    __syncthreads();
    for (int off = 128; off > 0; off >>= 1) {
        if (tid < off) { rs[tid] += rs[tid + off]; rq[tid] += rq[tid + off]; }
        __syncthreads();
    }
    if (tid == 0) {
        float mean = rs[0] / (float)NTV;
        float var  = rq[0] / (float)NTV - mean * mean;   // biased, like jnp.var
        stats[o]      = mean;
        stats[64 + o] = rsqrtf(var + BN_EPS);
    }
}

// ---------------------------------------------------------------------------
// Pass 3: out = relu(gamma*(pre-mean)*rsig + beta + x), in place, float4
// ---------------------------------------------------------------------------
__global__ __launch_bounds__(256) void gcn_finalize(
    const float* __restrict__ x, const float* __restrict__ gamma,
    const float* __restrict__ beta, const float* __restrict__ stats,
    float* __restrict__ out)
{
    const int total4 = (N_DIM * C_DIM * T_DIM * V_DIM) / 4;
    for (int i = blockIdx.x * blockDim.x + threadIdx.x; i < total4;
         i += gridDim.x * blockDim.x) {
        int chan = ((i * 4) / (T_DIM * V_DIM)) & 63;   // 12800 elems/channel, %4==0
        float4 p  = ((const float4*)out)[i];
        float4 xv = ((const float4*)x)[i];
        float m = stats[chan], r = stats[64 + chan];
        float g = gamma[chan] * r;
        float bc = beta[chan] - g * m;
        p.x = fmaxf(fmaf(g, p.x, bc) + xv.x, 0.f);
        p.y = fmaxf(fmaf(g, p.y, bc) + xv.y, 0.f);
        p.z = fmaxf(fmaf(g, p.z, bc) + xv.z, 0.f);
        p.w = fmaxf(fmaf(g, p.w, bc) + xv.w, 0.f);
        ((float4*)out)[i] = p;
    }
}

extern "C" void kernel_launch(void* const* d_in, const int* in_sizes, int n_in,
                              void* d_out, int out_size, void* d_ws, size_t ws_size,
                              hipStream_t stream) {
    const float* x     = (const float*)d_in[0];
    const float* A     = (const float*)d_in[1];
    const float* W     = (const float*)d_in[2];
    // d_in[3] = b : unused — per-channel bias cancels exactly through BatchNorm
    const float* gamma = (const float*)d_in[4];
    const float* beta  = (const float*)d_in[5];
    float* out = (float*)d_out;

    float* partial = (float*)d_ws;               // NBLK * 128 floats = 2 MB
    float* stats   = partial + NBLK * 128;       // 128 floats

    gcn_pass1<<<NBLK, 256, 0, stream>>>(x, A, W, out, partial);
    gcn_stats<<<64, 256, 0, stream>>>(partial, stats);
    gcn_finalize<<<2048, 256, 0, stream>>>(x, gamma, beta, stats, out);
}

// Round 3
// 131.739 us; speedup vs baseline: 2.9897x; 1.3286x over previous
//
#include <hip/hip_runtime.h>

// Problem dims (fixed by the reference)
#define N_DIM 32
#define C_DIM 64
#define T_DIM 512
#define V_DIM 25
#define H_DIM 3
#define TT 8                              // t-values per block in pass 1
#define NBLK (N_DIM * (T_DIM / TT))       // 2048 blocks in pass 1
#define NTV (N_DIM * T_DIM * V_DIM)       // 409600 elements per channel
#define XPITCH 76                         // shorts per tu-row (152 B): staging b64
                                          // writes and frag b64 reads conflict-free
#define BN_EPS 1e-5f

typedef float f32x4 __attribute__((ext_vector_type(4)));
typedef short bf16x8 __attribute__((ext_vector_type(8)));

__device__ __forceinline__ short f2bf(float f) {
    unsigned u = __float_as_uint(f);
    u = (u + 0x7FFFu + ((u >> 16) & 1u)) >> 16;   // round-to-nearest-even
    return (short)u;
}

__device__ __forceinline__ bf16x8 ld_bf8(const short* p) {   // two b64 LDS reads
    short4 a = *(const short4*)p;
    short4 b = *(const short4*)(p + 4);
    bf16x8 r;
    r[0] = a.x; r[1] = a.y; r[2] = a.z; r[3] = a.w;
    r[4] = b.x; r[5] = b.y; r[6] = b.z; r[7] = b.w;
    return r;
}

// ---------------------------------------------------------------------------
// Pass 1 (register-fused MFMA):
//   out_pre[n,o,t,v] = sum_{h,c,u} W[h,o,c] A[h,v,u] x[n,c,t,u]
// GEMM1 per (t,uh): D1[u'][o] = mfma(A=x-frag rows u', B=W-frag cols o), K=c=64.
//   A-frag row m is read from u(m) = (m>>2)*8 + uh*4 + (m&3), so lane (l15,hi)
//   ends up holding y[u = hi*8 + uh*4 + j][o = l15] — exactly the B-fragment
//   layout GEMM2 needs (k = hi*8+i). y never touches LDS.
// GEMM2 per t: acc[v][o] += mfma(A = A_h-frag rows v, B = y-frag), K=u pad 32.
//   A_h frag is zero for u>=25 or v>=25, nullifying all padding garbage.
// bias dropped: a per-channel constant cancels exactly through BatchNorm.
// ---------------------------------------------------------------------------
__global__ __launch_bounds__(256) void gcn_pass1(
    const float* __restrict__ x, const float* __restrict__ A,
    const float* __restrict__ W, float* __restrict__ out_pre,
    float* __restrict__ partial)
{
    __shared__ __align__(16) short x_sT[208 * XPITCH];   // 31,616 B

    const int blk  = blockIdx.x;
    const int n    = blk >> 6;             // 64 t-groups per n
    const int t0   = (blk & 63) * TT;
    const int tid  = threadIdx.x;
    const int lane = tid & 63;
    const int w    = tid >> 6;             // wave 0..3 -> o in [16w, 16w+16)
    const int l15  = lane & 15;
    const int hi   = lane >> 4;

    // ---- W fragments: lane: o = 16w + l15, k(c) = s*32 + hi*8 + i
    bf16x8 wf[H_DIM][2];
    #pragma unroll
    for (int h = 0; h < H_DIM; ++h)
        #pragma unroll
        for (int s = 0; s < 2; ++s) {
            const f32x4* wp = (const f32x4*)(W + h * 4096 + (16 * w + l15) * 64
                                             + s * 32 + hi * 8);
            f32x4 lo = wp[0], hv = wp[1];
            bf16x8 f;
            #pragma unroll
            for (int i = 0; i < 4; ++i) { f[i] = f2bf(lo[i]); f[4 + i] = f2bf(hv[i]); }
            wf[h][s] = f;
        }

    // ---- A fragments: lane: v = vt*16 + l15, k(u) = hi*8 + i; zero pads
    bf16x8 af[H_DIM][2];
    #pragma unroll
    for (int h = 0; h < H_DIM; ++h)
        #pragma unroll
        for (int vt = 0; vt < 2; ++vt) {
            int v = vt * 16 + l15;
            bf16x8 f;
            #pragma unroll
            for (int i = 0; i < 8; ++i) {
                int u = hi * 8 + i;
                f[i] = (v < 25 && u < 25) ? f2bf(A[h * 625 + v * 25 + u]) : (short)0;
            }
            af[h][vt] = f;
        }

    // ---- stage x transposed: x_sT[tu][c], b64 writes, 4 coalesced load streams
    const float* xn = x + (size_t)n * (C_DIM * T_DIM * V_DIM) + t0 * 25;
    for (int e = tid; e < 3200; e += 256) {
        int cg = e / 200, tu = e - cg * 200;
        float f0 = xn[(4 * cg + 0) * 12800 + tu];
        float f1 = xn[(4 * cg + 1) * 12800 + tu];
        float f2 = xn[(4 * cg + 2) * 12800 + tu];
        float f3 = xn[(4 * cg + 3) * 12800 + tu];
        short4 p; p.x = f2bf(f0); p.y = f2bf(f1); p.z = f2bf(f2); p.w = f2bf(f3);
        *(short4*)&x_sT[tu * XPITCH + 4 * cg] = p;
    }
    // zero pad rows 200..207 (avoid stale-LDS NaN patterns reaching MFMA)
    for (int e = tid; e < (8 * XPITCH) / 2; e += 256)
        ((int*)&x_sT[200 * XPITCH])[e] = 0;
    __syncthreads();

    // per-lane x-row base for the u-permutation: u = (l15>>2)*8 + uh*4 + (l15&3)
    const int ubase = ((l15 >> 2) * 8) + (l15 & 3);

    float s_tot = 0.f, q_tot = 0.f;

    for (int t = 0; t < TT; ++t) {
        const short* xr0 = &x_sT[(t * 25 + ubase + 0) * XPITCH + hi * 8];  // uh=0
        const short* xr1 = &x_sT[(t * 25 + ubase + 4) * XPITCH + hi * 8];  // uh=1
        const bf16x8 xf00 = ld_bf8(xr0), xf01 = ld_bf8(xr0 + 32);
        const bf16x8 xf10 = ld_bf8(xr1), xf11 = ld_bf8(xr1 + 32);

        f32x4 acc2[2] = {f32x4{0.f, 0.f, 0.f, 0.f}, f32x4{0.f, 0.f, 0.f, 0.f}};

        #pragma unroll
        for (int h = 0; h < H_DIM; ++h) {
            f32x4 y0 = {0.f, 0.f, 0.f, 0.f}, y1 = {0.f, 0.f, 0.f, 0.f};
            y0 = __builtin_amdgcn_mfma_f32_16x16x32_bf16(xf00, wf[h][0], y0, 0, 0, 0);
            y0 = __builtin_amdgcn_mfma_f32_16x16x32_bf16(xf01, wf[h][1], y0, 0, 0, 0);
            y1 = __builtin_amdgcn_mfma_f32_16x16x32_bf16(xf10, wf[h][0], y1, 0, 0, 0);
            y1 = __builtin_amdgcn_mfma_f32_16x16x32_bf16(xf11, wf[h][1], y1, 0, 0, 0);
            bf16x8 yf;
            #pragma unroll
            for (int j = 0; j < 4; ++j) { yf[j] = f2bf(y0[j]); yf[4 + j] = f2bf(y1[j]); }
            acc2[0] = __builtin_amdgcn_mfma_f32_16x16x32_bf16(af[h][0], yf, acc2[0], 0, 0, 0);
            acc2[1] = __builtin_amdgcn_mfma_f32_16x16x32_bf16(af[h][1], yf, acc2[1], 0, 0, 0);
        }

        // ---- store pre-BN: lane owns o = 16w+l15; rows v = vt*16 + hi*4 + j
        float* op = out_pre + ((size_t)(n * 64 + 16 * w + l15) * 512 + (t0 + t)) * 25;
        #pragma unroll
        for (int j = 0; j < 4; ++j) op[hi * 4 + j] = acc2[0][j];
        if (hi < 2) {
            #pragma unroll
            for (int j = 0; j < 4; ++j) op[16 + hi * 4 + j] = acc2[1][j];
        } else if (hi == 2) {
            op[24] = acc2[1][0];
        }

        // ---- stats for this t (v<25 only), reduce across hi-groups (same o)
        float s = 0.f, q = 0.f;
        #pragma unroll
        for (int j = 0; j < 4; ++j) { float v0 = acc2[0][j]; s += v0; q = fmaf(v0, v0, q); }
        #pragma unroll
        for (int j = 0; j < 4; ++j) {
            if (hi * 4 + j < 9) { float v1 = acc2[1][j]; s += v1; q = fmaf(v1, v1, q); }
        }
        s += __shfl_xor(s, 16); q += __shfl_xor(q, 16);
        s += __shfl_xor(s, 32); q += __shfl_xor(q, 32);
        s_tot += s; q_tot += q;
    }

    if (hi == 0) {
        int o = 16 * w + l15;
        partial[blk * 128 + o]      = s_tot;
        partial[blk * 128 + 64 + o] = q_tot;
    }
}

// ---------------------------------------------------------------------------
// Pass 2: reduce partials -> per-channel mean and rsqrt(var+eps)
// ---------------------------------------------------------------------------
__global__ __launch_bounds__(256) void gcn_stats(
    const float* __restrict__ partial, float* __restrict__ stats)
{
    const int o = blockIdx.x;      // 64 blocks, one per channel
    const int tid = threadIdx.x;
    float s = 0.f, q = 0.f;
    for (int blk = tid; blk < NBLK; blk += 256) {
        s += partial[blk * 128 + o];
        q += partial[blk * 128 + 64 + o];
    }
    __shared__ float rs[256], rq[256];
    rs[tid] = s; rq[tid] = q;
    __syncthreads();
    for (int off = 128; off > 0; off >>= 1) {
        if (tid < off) { rs[tid] += rs[tid + off]; rq[tid] += rq[tid + off]; }
        __syncthreads();
    }
    if (tid == 0) {
        float mean = rs[0] / (float)NTV;
        float var  = rq[0] / (float)NTV - mean * mean;   // biased, like jnp.var
        stats[o]      = mean;
        stats[64 + o] = rsqrtf(var + BN_EPS);
    }
}

// ---------------------------------------------------------------------------
// Pass 3: out = relu(gamma*(pre-mean)*rsig + beta + x), in place, float4
// ---------------------------------------------------------------------------
__global__ __launch_bounds__(256) void gcn_finalize(
    const float* __restrict__ x, const float* __restrict__ gamma,
    const float* __restrict__ beta, const float* __restrict__ stats,
    float* __restrict__ out)
{
    const int total4 = (N_DIM * C_DIM * T_DIM * V_DIM) / 4;
    for (int i = blockIdx.x * blockDim.x + threadIdx.x; i < total4;
         i += gridDim.x * blockDim.x) {
        int chan = ((i * 4) / (T_DIM * V_DIM)) & 63;   // 12800 elems/channel, %4==0
        float4 p  = ((const float4*)out)[i];
        float4 xv = ((const float4*)x)[i];
        float m = stats[chan], r = stats[64 + chan];
        float g = gamma[chan] * r;
        float bc = beta[chan] - g * m;
        p.x = fmaxf(fmaf(g, p.x, bc) + xv.x, 0.f);
        p.y = fmaxf(fmaf(g, p.y, bc) + xv.y, 0.f);
        p.z = fmaxf(fmaf(g, p.z, bc) + xv.z, 0.f);
        p.w = fmaxf(fmaf(g, p.w, bc) + xv.w, 0.f);
        ((float4*)out)[i] = p;
    }
}

extern "C" void kernel_launch(void* const* d_in, const int* in_sizes, int n_in,
                              void* d_out, int out_size, void* d_ws, size_t ws_size,
                              hipStream_t stream) {
    const float* x     = (const float*)d_in[0];
    const float* A     = (const float*)d_in[1];
    const float* W     = (const float*)d_in[2];
    // d_in[3] = b : unused — per-channel bias cancels exactly through BatchNorm
    const float* gamma = (const float*)d_in[4];
    const float* beta  = (const float*)d_in[5];
    float* out = (float*)d_out;

    float* partial = (float*)d_ws;               // NBLK * 128 floats = 1 MB
    float* stats   = partial + NBLK * 128;       // 128 floats

    gcn_pass1<<<NBLK, 256, 0, stream>>>(x, A, W, out, partial);
    gcn_stats<<<64, 256, 0, stream>>>(partial, stats);
    gcn_finalize<<<2048, 256, 0, stream>>>(x, gamma, beta, stats, out);
}

// Round 4
// 125.037 us; speedup vs baseline: 3.1499x; 1.0536x over previous
//
#include <hip/hip_runtime.h>
#include <hip/hip_bf16.h>

// Problem dims (fixed by the reference)
#define N_DIM 32
#define C_DIM 64
#define T_DIM 512
#define V_DIM 25
#define H_DIM 3
#define TT 8                              // t-values per block in pass 1
#define NBLK (N_DIM * (T_DIM / TT))       // 2048 blocks in pass 1
#define NTV (N_DIM * T_DIM * V_DIM)       // 409600 elements per channel
#define NTOT (N_DIM * C_DIM * T_DIM * V_DIM)
#define XPITCH 76                         // shorts per tu-row (152 B)
#define VP 28                             // padded v-pitch of bf16 scratch
#define BN_EPS 1e-5f

typedef float f32x4 __attribute__((ext_vector_type(4)));
typedef short bf16x8 __attribute__((ext_vector_type(8)));
typedef short s16x4 __attribute__((ext_vector_type(4)));

__device__ __forceinline__ short f2bf(float f) {
    __hip_bfloat16 h = __float2bfloat16(f);   // RNE; pairs fuse to v_cvt_pk_bf16_f32
    return __builtin_bit_cast(short, h);
}

__device__ __forceinline__ bf16x8 ld_bf8(const short* p) {   // two b64 LDS reads
    s16x4 a = *(const s16x4*)p;
    s16x4 b = *(const s16x4*)(p + 4);
    bf16x8 r;
    r[0] = a[0]; r[1] = a[1]; r[2] = a[2]; r[3] = a[3];
    r[4] = b[0]; r[5] = b[1]; r[6] = b[2]; r[7] = b[3];
    return r;
}

// ---------------------------------------------------------------------------
// Pass 1 (register-fused MFMA):
//   out_pre[n,o,t,v] = sum_{h,c,u} W[h,o,c] A[h,v,u] x[n,c,t,u]
// GEMM1 per (t,uh): D1[u'][o] = mfma(A=x-frag rows u', B=W-frag cols o), K=c=64.
//   A-frag row m reads u(m) = (m>>2)*8 + uh*4 + (m&3), so lane (l15,hi) ends up
//   holding y[u = hi*8 + uh*4 + j][o = l15] — exactly GEMM2's B-fragment. y
//   never touches LDS.
// GEMM2 per t: acc[v][o] += mfma(A = A_h rows v, B = y-frag), K=u pad 32.
// SCR=1: bf16 scratch [n][o][t][VP] in d_ws, vector short4 stores.
// SCR=0: fp32 scratch = d_out in final layout, scalar stores (fallback).
// bias dropped: per-channel constant cancels exactly through BatchNorm.
// ---------------------------------------------------------------------------
template <int SCR>
__global__ __launch_bounds__(256) void gcn_pass1(
    const float* __restrict__ x, const float* __restrict__ A,
    const float* __restrict__ W, void* __restrict__ scratch_,
    float* __restrict__ partial)
{
    __shared__ __align__(16) short x_sT[208 * XPITCH];   // 31,616 B

    const int blk  = blockIdx.x;
    const int n    = blk >> 6;             // 64 t-groups per n
    const int t0   = (blk & 63) * TT;
    const int tid  = threadIdx.x;
    const int lane = tid & 63;
    const int w    = tid >> 6;             // wave 0..3 -> o in [16w, 16w+16)
    const int l15  = lane & 15;
    const int hi   = lane >> 4;

    // ---- W fragments: lane: o = 16w + l15, k(c) = s*32 + hi*8 + i
    bf16x8 wf[H_DIM][2];
    #pragma unroll
    for (int h = 0; h < H_DIM; ++h)
        #pragma unroll
        for (int s = 0; s < 2; ++s) {
            const f32x4* wp = (const f32x4*)(W + h * 4096 + (16 * w + l15) * 64
                                             + s * 32 + hi * 8);
            f32x4 lo = wp[0], hv = wp[1];
            bf16x8 f;
            #pragma unroll
            for (int i = 0; i < 4; ++i) { f[i] = f2bf(lo[i]); f[4 + i] = f2bf(hv[i]); }
            wf[h][s] = f;
        }

    // ---- A fragments: lane: v = vt*16 + l15, k(u) = hi*8 + i; zero pads
    bf16x8 af[H_DIM][2];
    #pragma unroll
    for (int h = 0; h < H_DIM; ++h)
        #pragma unroll
        for (int vt = 0; vt < 2; ++vt) {
            int v = vt * 16 + l15;
            bf16x8 f;
            #pragma unroll
            for (int i = 0; i < 8; ++i) {
                int u = hi * 8 + i;
                f[i] = (v < 25 && u < 25) ? f2bf(A[h * 625 + v * 25 + u]) : (short)0;
            }
            af[h][vt] = f;
        }

    // ---- stage x transposed: x_sT[tu][c], b64 writes, 4 coalesced load streams
    const float* xn = x + (size_t)n * (C_DIM * T_DIM * V_DIM) + t0 * 25;
    for (int e = tid; e < 3200; e += 256) {
        int cg = e / 200, tu = e - cg * 200;
        float f0 = xn[(4 * cg + 0) * 12800 + tu];
        float f1 = xn[(4 * cg + 1) * 12800 + tu];
        float f2 = xn[(4 * cg + 2) * 12800 + tu];
        float f3 = xn[(4 * cg + 3) * 12800 + tu];
        s16x4 p; p[0] = f2bf(f0); p[1] = f2bf(f1); p[2] = f2bf(f2); p[3] = f2bf(f3);
        *(s16x4*)&x_sT[tu * XPITCH + 4 * cg] = p;
    }
    // zero pad rows 200..207 (avoid stale-LDS NaN patterns reaching MFMA)
    for (int e = tid; e < (8 * XPITCH) / 2; e += 256)
        ((int*)&x_sT[200 * XPITCH])[e] = 0;
    __syncthreads();

    // per-lane x-row base for the u-permutation: u = (l15>>2)*8 + uh*4 + (l15&3)
    const int ubase = ((l15 >> 2) * 8) + (l15 & 3);

    float s_tot = 0.f, q_tot = 0.f;
    const int o_glob = 16 * w + l15;

    for (int t = 0; t < TT; ++t) {
        const short* xr0 = &x_sT[(t * 25 + ubase + 0) * XPITCH + hi * 8];  // uh=0
        const short* xr1 = &x_sT[(t * 25 + ubase + 4) * XPITCH + hi * 8];  // uh=1
        const bf16x8 xf00 = ld_bf8(xr0), xf01 = ld_bf8(xr0 + 32);
        const bf16x8 xf10 = ld_bf8(xr1), xf11 = ld_bf8(xr1 + 32);

        f32x4 acc2[2] = {f32x4{0.f, 0.f, 0.f, 0.f}, f32x4{0.f, 0.f, 0.f, 0.f}};

        #pragma unroll
        for (int h = 0; h < H_DIM; ++h) {
            f32x4 y0 = {0.f, 0.f, 0.f, 0.f}, y1 = {0.f, 0.f, 0.f, 0.f};
            y0 = __builtin_amdgcn_mfma_f32_16x16x32_bf16(xf00, wf[h][0], y0, 0, 0, 0);
            y0 = __builtin_amdgcn_mfma_f32_16x16x32_bf16(xf01, wf[h][1], y0, 0, 0, 0);
            y1 = __builtin_amdgcn_mfma_f32_16x16x32_bf16(xf10, wf[h][0], y1, 0, 0, 0);
            y1 = __builtin_amdgcn_mfma_f32_16x16x32_bf16(xf11, wf[h][1], y1, 0, 0, 0);
            bf16x8 yf;
            #pragma unroll
            for (int j = 0; j < 4; ++j) yf[j] = f2bf(y0[j]);
            #pragma unroll
            for (int j = 0; j < 4; ++j) yf[4 + j] = f2bf(y1[j]);
            acc2[0] = __builtin_amdgcn_mfma_f32_16x16x32_bf16(af[h][0], yf, acc2[0], 0, 0, 0);
            acc2[1] = __builtin_amdgcn_mfma_f32_16x16x32_bf16(af[h][1], yf, acc2[1], 0, 0, 0);
        }

        if (SCR) {
            // bf16 scratch [n][o][t][VP]: short4 stores, 8B-aligned
            short* sp = (short*)scratch_
                      + ((size_t)(n * 64 + o_glob) * 512 + (t0 + t)) * VP;
            s16x4 p0; p0[0] = f2bf(acc2[0][0]); p0[1] = f2bf(acc2[0][1]);
                      p0[2] = f2bf(acc2[0][2]); p0[3] = f2bf(acc2[0][3]);
            *(s16x4*)(sp + hi * 4) = p0;               // v = hi*4 .. hi*4+3
            if (hi < 2) {
                s16x4 p1; p1[0] = f2bf(acc2[1][0]); p1[1] = f2bf(acc2[1][1]);
                          p1[2] = f2bf(acc2[1][2]); p1[3] = f2bf(acc2[1][3]);
                *(s16x4*)(sp + 16 + hi * 4) = p1;      // v = 16+hi*4 ..
            } else if (hi == 2) {
                sp[24] = f2bf(acc2[1][0]);             // v = 24
            }
        } else {
            float* op = (float*)scratch_
                      + ((size_t)(n * 64 + o_glob) * 512 + (t0 + t)) * 25;
            #pragma unroll
            for (int j = 0; j < 4; ++j) op[hi * 4 + j] = acc2[0][j];
            if (hi < 2) {
                #pragma unroll
                for (int j = 0; j < 4; ++j) op[16 + hi * 4 + j] = acc2[1][j];
            } else if (hi == 2) {
                op[24] = acc2[1][0];
            }
        }

        // ---- per-lane stats accumulate (shuffle hoisted out of loop)
        float s = acc2[0][0] + acc2[0][1] + acc2[0][2] + acc2[0][3];
        float q = fmaf(acc2[0][0], acc2[0][0], fmaf(acc2[0][1], acc2[0][1],
                  fmaf(acc2[0][2], acc2[0][2], acc2[0][3] * acc2[0][3])));
        if (hi < 2) {
            #pragma unroll
            for (int j = 0; j < 4; ++j) {
                float v1 = acc2[1][j]; s += v1; q = fmaf(v1, v1, q);
            }
        } else if (hi == 2) {
            float v1 = acc2[1][0]; s += v1; q = fmaf(v1, v1, q);
        }
        s_tot += s; q_tot += q;
    }

    s_tot += __shfl_xor(s_tot, 16); q_tot += __shfl_xor(q_tot, 16);
    s_tot += __shfl_xor(s_tot, 32); q_tot += __shfl_xor(q_tot, 32);
    if (hi == 0) {
        partial[blk * 128 + o_glob]      = s_tot;
        partial[blk * 128 + 64 + o_glob] = q_tot;
    }
}

// ---------------------------------------------------------------------------
// Pass 2: reduce partials -> per-channel mean and rsqrt(var+eps)
// ---------------------------------------------------------------------------
__global__ __launch_bounds__(256) void gcn_stats(
    const float* __restrict__ partial, float* __restrict__ stats)
{
    const int o = blockIdx.x;      // 64 blocks, one per channel
    const int tid = threadIdx.x;
    float s = 0.f, q = 0.f;
    for (int blk = tid; blk < NBLK; blk += 256) {
        s += partial[blk * 128 + o];
        q += partial[blk * 128 + 64 + o];
    }
    __shared__ float rs[256], rq[256];
    rs[tid] = s; rq[tid] = q;
    __syncthreads();
    for (int off = 128; off > 0; off >>= 1) {
        if (tid < off) { rs[tid] += rs[tid + off]; rq[tid] += rq[tid + off]; }
        __syncthreads();
    }
    if (tid == 0) {
        float mean = rs[0] / (float)NTV;
        float var  = rq[0] / (float)NTV - mean * mean;   // biased, like jnp.var
        stats[o]      = mean;
        stats[64 + o] = rsqrtf(var + BN_EPS);
    }
}

// ---------------------------------------------------------------------------
// Pass 3 (bf16-scratch): out = relu(gamma*(pre-mean)*rsig + beta + x), float4
// ---------------------------------------------------------------------------
__global__ __launch_bounds__(256) void gcn_finalize_b(
    const float* __restrict__ x, const float* __restrict__ gamma,
    const float* __restrict__ beta, const float* __restrict__ stats,
    const unsigned short* __restrict__ scr, float* __restrict__ out)
{
    const int total4 = NTOT / 4;
    for (int i = blockIdx.x * blockDim.x + threadIdx.x; i < total4;
         i += gridDim.x * blockDim.x) {
        int e0 = i * 4;
        unsigned r = (unsigned)(((unsigned long long)e0 * 0x51EB851Full) >> 35); // /25
        int v0 = e0 - (int)r * 25;
        float4 xv = ((const float4*)x)[i];
        float res[4];
        #pragma unroll
        for (int k = 0; k < 4; ++k) {
            unsigned rr = r; int vv = v0 + k;
            if (vv >= 25) { rr = r + 1; vv -= 25; }    // at most one carry
            int chan = (rr >> 9) & 63;
            float pv = __uint_as_float((unsigned)scr[(size_t)rr * VP + vv] << 16);
            float m = stats[chan], rs = stats[64 + chan];
            float g = gamma[chan] * rs;
            float bc = beta[chan] - g * m;
            float xk = (&xv.x)[k];
            res[k] = fmaxf(fmaf(g, pv, bc) + xk, 0.f);
        }
        float4 o4; o4.x = res[0]; o4.y = res[1]; o4.z = res[2]; o4.w = res[3];
        ((float4*)out)[i] = o4;
    }
}

// ---------------------------------------------------------------------------
// Pass 3 (fallback, fp32 scratch == out): in-place elementwise
// ---------------------------------------------------------------------------
__global__ __launch_bounds__(256) void gcn_finalize_f(
    const float* __restrict__ x, const float* __restrict__ gamma,
    const float* __restrict__ beta, const float* __restrict__ stats,
    float* __restrict__ out)
{
    const int total4 = NTOT / 4;
    for (int i = blockIdx.x * blockDim.x + threadIdx.x; i < total4;
         i += gridDim.x * blockDim.x) {
        int chan = ((i * 4) / (T_DIM * V_DIM)) & 63;
        float4 p  = ((const float4*)out)[i];
        float4 xv = ((const float4*)x)[i];
        float m = stats[chan], r = stats[64 + chan];
        float g = gamma[chan] * r;
        float bc = beta[chan] - g * m;
        p.x = fmaxf(fmaf(g, p.x, bc) + xv.x, 0.f);
        p.y = fmaxf(fmaf(g, p.y, bc) + xv.y, 0.f);
        p.z = fmaxf(fmaf(g, p.z, bc) + xv.z, 0.f);
        p.w = fmaxf(fmaf(g, p.w, bc) + xv.w, 0.f);
        ((float4*)out)[i] = p;
    }
}

extern "C" void kernel_launch(void* const* d_in, const int* in_sizes, int n_in,
                              void* d_out, int out_size, void* d_ws, size_t ws_size,
                              hipStream_t stream) {
    const float* x     = (const float*)d_in[0];
    const float* A     = (const float*)d_in[1];
    const float* W     = (const float*)d_in[2];
    // d_in[3] = b : unused — per-channel bias cancels exactly through BatchNorm
    const float* gamma = (const float*)d_in[4];
    const float* beta  = (const float*)d_in[5];
    float* out = (float*)d_out;

    const size_t scr_bytes  = (size_t)N_DIM * C_DIM * T_DIM * VP * 2;   // 58.7 MB
    const size_t part_bytes = (size_t)(NBLK * 128 + 128) * 4;

    if (ws_size >= scr_bytes + part_bytes) {
        unsigned short* scr = (unsigned short*)d_ws;
        float* partial = (float*)((char*)d_ws + scr_bytes);
        float* stats   = partial + NBLK * 128;
        gcn_pass1<1><<<NBLK, 256, 0, stream>>>(x, A, W, (void*)scr, partial);
        gcn_stats<<<64, 256, 0, stream>>>(partial, stats);
        gcn_finalize_b<<<2048, 256, 0, stream>>>(x, gamma, beta, stats, scr, out);
    } else {
        float* partial = (float*)d_ws;
        float* stats   = partial + NBLK * 128;
        gcn_pass1<0><<<NBLK, 256, 0, stream>>>(x, A, W, (void*)out, partial);
        gcn_stats<<<64, 256, 0, stream>>>(partial, stats);
        gcn_finalize_f<<<2048, 256, 0, stream>>>(x, gamma, beta, stats, out);
    }
}